// Round 3
// baseline (347.231 us; speedup 1.0000x reference)
//
#include <hip/hip_runtime.h>
#include <cstdint>

constexpr int Bv = 16, Nv = 4096, Fv = 512, Sv = 8, Kv = 1024, Dv = 64;
constexpr int Mv = Bv * Nv;  // 65536 rows
#define BDIM 256

using bf16x8 = __attribute__((ext_vector_type(8))) short;
using f32x4  = __attribute__((ext_vector_type(4))) float;
typedef unsigned short u16;
typedef unsigned int u32;

__device__ __forceinline__ u16 bf16rne(float f) {
  union { float f; u32 u; } v; v.f = f;
  u32 u = v.u + 0x7FFFu + ((v.u >> 16) & 1u);
  return (u16)(u >> 16);
}

__device__ __forceinline__ void gload_lds16(const void* g, void* lds) {
  __builtin_amdgcn_global_load_lds(
      (const __attribute__((address_space(1))) void*)g,
      (__attribute__((address_space(3))) void*)lds, 16, 0, 0);
}

// prep: cb fp32 -> (a) swizzled bf16 codebook, (b) c2m = -0.5*sum(c^2) (argmax form)
// swz layout: [s*1024+cw][slot'][8 bf16], slot' = slot ^ (cw&7)
__global__ void prep_kernel(const float* __restrict__ cb, u16* __restrict__ swz,
                            float* __restrict__ c2m) {
  int idx = blockIdx.x * BDIM + threadIdx.x;  // s*1024+cw
  int cw = idx & (Kv - 1);
  const float4* src = (const float4*)(cb + (size_t)idx * Dv);
  float v[64];
  float s2 = 0.f;
#pragma unroll
  for (int i = 0; i < 16; ++i) {
    float4 f = src[i];
    v[i * 4 + 0] = f.x; v[i * 4 + 1] = f.y; v[i * 4 + 2] = f.z; v[i * 4 + 3] = f.w;
    s2 += f.x * f.x + f.y * f.y + f.z * f.z + f.w * f.w;
  }
  c2m[idx] = -0.5f * s2;
  uint4* out = (uint4*)(swz + (size_t)idx * Dv);
#pragma unroll
  for (int slot = 0; slot < 8; ++slot) {
    int slotp = slot ^ (cw & 7);
    u32 w[4];
#pragma unroll
    for (int p = 0; p < 4; ++p)
      w[p] = (u32)bf16rne(v[slot * 8 + p * 2]) | ((u32)bf16rne(v[slot * 8 + p * 2 + 1]) << 16);
    uint4 pk; pk.x = w[0]; pk.y = w[1]; pk.z = w[2]; pk.w = w[3];
    out[slotp] = pk;
  }
}

// main: block = 256 rows x 1 subspace; wave = 64 rows x all 1024 codewords.
// score = <x,c> - 0.5*c2 via mfma(A=cb_bf16, B=x_bf16, C=c2m); lane-local argMAX.
__global__ __launch_bounds__(BDIM, 8) void pq_mfma(
    const float* __restrict__ x, const float* __restrict__ cb,
    const u16* __restrict__ swz, const float* __restrict__ c2m_g,
    float* __restrict__ quant, float* __restrict__ devpart) {
  __shared__ __attribute__((aligned(16))) u16 cb_lds[2][64 * Dv];  // 2 x 8KB
  __shared__ __attribute__((aligned(16))) float c2_lds[Kv];        // 4KB

  const int tid = threadIdx.x;
  const int s = blockIdx.y;
  const int row0 = blockIdx.x * 256;
  const int wave = tid >> 6, lane = tid & 63;
  const int l15 = lane & 15, lg = lane >> 4;
  const int slotp0 = lg ^ (lane & 7);
  const int slotp1 = (4 + lg) ^ (lane & 7);

  // stage c2 (4KB, one instr) + chunk 0 (8KB, two instr); linear LDS dest
  gload_lds16(c2m_g + s * Kv + tid * 4, &c2_lds[(tid & ~63) * 4]);
  const u16* swz_s = swz + (size_t)s * Kv * Dv;
#pragma unroll
  for (int it = 0; it < 2; ++it)
    gload_lds16(swz_s + (size_t)(it * BDIM + tid) * 8,
                &cb_lds[0][(it * BDIM + (tid & ~63)) * 8]);

  // x rows -> bf16 fragments + fp32 x2 partials
  bf16x8 xf[4][2];
  float x2p[4];
#pragma unroll
  for (int rg = 0; rg < 4; ++rg) {
    x2p[rg] = 0.f;
    const int row = row0 + wave * 64 + rg * 16 + l15;
    const float* xp = x + (size_t)row * Fv + s * Dv + lg * 8;
#pragma unroll
    for (int h = 0; h < 2; ++h) {
      float4 f0 = *(const float4*)(xp + h * 32);
      float4 f1 = *(const float4*)(xp + h * 32 + 4);
      x2p[rg] += f0.x * f0.x + f0.y * f0.y + f0.z * f0.z + f0.w * f0.w
               + f1.x * f1.x + f1.y * f1.y + f1.z * f1.z + f1.w * f1.w;
      bf16x8 v;
      v[0] = (short)bf16rne(f0.x); v[1] = (short)bf16rne(f0.y);
      v[2] = (short)bf16rne(f0.z); v[3] = (short)bf16rne(f0.w);
      v[4] = (short)bf16rne(f1.x); v[5] = (short)bf16rne(f1.y);
      v[6] = (short)bf16rne(f1.z); v[7] = (short)bf16rne(f1.w);
      xf[rg][h] = v;
    }
  }

  float bestv[4];
  int besti[4];
#pragma unroll
  for (int rg = 0; rg < 4; ++rg) { bestv[rg] = -3.0e38f; besti[rg] = 0; }

  __syncthreads();

  // 16 chunks of 64 codewords, double-buffered
#pragma unroll 2
  for (int c = 0; c < 16; ++c) {
    if (c < 15) {
      const u16* srcb = swz_s + (size_t)(c + 1) * 64 * Dv;
#pragma unroll
      for (int it = 0; it < 2; ++it)
        gload_lds16(srcb + (size_t)(it * BDIM + tid) * 8,
                    &cb_lds[(c + 1) & 1][(it * BDIM + (tid & ~63)) * 8]);
    }
    const u16* cbb = cb_lds[c & 1];
    const int kc = c * 64 + lg * 4;
#pragma unroll
    for (int ct = 0; ct < 4; ++ct) {
      f32x4 c2v = *(const f32x4*)&c2_lds[c * 64 + ct * 16 + lg * 4];
      const u16* ap = &cbb[(ct * 16 + l15) * Dv];
      bf16x8 a0 = *(const bf16x8*)&ap[slotp0 * 8];
      bf16x8 a1 = *(const bf16x8*)&ap[slotp1 * 8];
#pragma unroll
      for (int rg = 0; rg < 4; ++rg) {
        f32x4 acc = __builtin_amdgcn_mfma_f32_16x16x32_bf16(a0, xf[rg][0], c2v, 0, 0, 0);
        acc = __builtin_amdgcn_mfma_f32_16x16x32_bf16(a1, xf[rg][1], acc, 0, 0, 0);
#pragma unroll
        for (int r = 0; r < 4; ++r) {
          float v = acc[r];
          int ki = kc + ct * 16 + r;
          bool p = v > bestv[rg];
          bestv[rg] = p ? v : bestv[rg];
          besti[rg] = p ? ki : besti[rg];
        }
      }
    }
    __syncthreads();
  }

  // cross-lane argmax + x2 reduce over lg (cols l15 preserved)
#pragma unroll
  for (int rg = 0; rg < 4; ++rg) {
    float bv = bestv[rg]; int bi = besti[rg]; float xx = x2p[rg];
#pragma unroll
    for (int st = 0; st < 2; ++st) {
      const int m = st == 0 ? 16 : 32;
      float ov = __shfl_xor(bv, m, 64);
      int oi = __shfl_xor(bi, m, 64);
      xx += __shfl_xor(xx, m, 64);
      bool p = (ov > bv) || (ov == bv && oi < bi);
      bv = p ? ov : bv; bi = p ? oi : bi;
    }
    bestv[rg] = bv; besti[rg] = bi; x2p[rg] = xx;
  }

  // dev partial: dist_row = x2 - 2*bestmax
  float dev = 0.f;
#pragma unroll
  for (int rg = 0; rg < 4; ++rg) dev += x2p[rg] - 2.f * bestv[rg];
#pragma unroll
  for (int m = 1; m <= 8; m <<= 1) dev += __shfl_xor(dev, m, 64);
  if (lane == 0)
    devpart[((size_t)blockIdx.y * gridDim.x + blockIdx.x) * 4 + wave] = dev;

  // redistribute best indices via LDS (reuse buf0; wave-private region, no barrier)
  int* idx_sh = (int*)&cb_lds[0][0];
  if (lg == 0) {
#pragma unroll
    for (int rg = 0; rg < 4; ++rg) idx_sh[wave * 64 + rg * 16 + l15] = besti[rg];
  }

  // coalesced quant write: instr i covers rows i*4+(lane>>4), full 256B segments
  const float* cbs = cb + (size_t)s * Kv * Dv;
  float* qbase = quant + (size_t)(row0 + wave * 64) * Fv + s * Dv;
#pragma unroll
  for (int i = 0; i < 16; ++i) {
    int rl = i * 4 + (lane >> 4);
    int k = idx_sh[wave * 64 + rl];
    float4 v = *(const float4*)(cbs + (size_t)k * Dv + (lane & 15) * 4);
    *(float4*)(qbase + (size_t)rl * Fv + (lane & 15) * 4) = v;
  }
}

__global__ void dev_reduce(const float* __restrict__ part, float* __restrict__ out) {
  __shared__ float sred[256];
  int tid = threadIdx.x;
  float s = 0.f;
  for (int i = tid; i < 8192; i += 256) s += part[i];
  sred[tid] = s;
  __syncthreads();
  for (int off = 128; off > 0; off >>= 1) {
    if (tid < off) sred[tid] += sred[tid + off];
    __syncthreads();
  }
  if (tid == 0) out[0] = sred[0] * (1.25f / 4194304.0f);
}

extern "C" void kernel_launch(void* const* d_in, const int* in_sizes, int n_in,
                              void* d_out, int out_size, void* d_ws, size_t ws_size,
                              hipStream_t stream) {
  const float* x = (const float*)d_in[0];   // (B,N,F) fp32
  const float* cb = (const float*)d_in[1];  // (S,K,D) fp32
  float* quant = (float*)d_out;
  float* dev = quant + (size_t)Mv * Fv;

  // ws: swz bf16 codebook (1MB), c2m (32KB), dev partials (32KB)
  u16* swz = (u16*)d_ws;
  float* c2m = (float*)(swz + (size_t)Sv * Kv * Dv);
  float* part = c2m + Sv * Kv;

  prep_kernel<<<(Sv * Kv) / BDIM, BDIM, 0, stream>>>(cb, swz, c2m);
  dim3 grid(Mv / 256, Sv);
  pq_mfma<<<grid, BDIM, 0, stream>>>(x, cb, swz, c2m, quant, part);
  dev_reduce<<<1, 256, 0, stream>>>(part, dev);
}

// Round 4
// 131.578 us; speedup vs baseline: 2.6390x; 2.6390x over previous
//
#include <hip/hip_runtime.h>
#include <cstdint>

constexpr int Bv = 16, Nv = 4096, Fv = 512, Sv = 8, Kv = 1024, Dv = 64;
constexpr int Mv = Bv * Nv;  // 65536 rows
#define BDIM 256

using bf16x8 = __attribute__((ext_vector_type(8))) short;
using f32x4  = __attribute__((ext_vector_type(4))) float;
typedef unsigned short u16;
typedef unsigned int u32;

__device__ __forceinline__ u16 bf16rne(float f) {
  union { float f; u32 u; } v; v.f = f;
  u32 u = v.u + 0x7FFFu + ((v.u >> 16) & 1u);
  return (u16)(u >> 16);
}

__device__ __forceinline__ void gload_lds16(const void* g, void* lds) {
  __builtin_amdgcn_global_load_lds(
      (const __attribute__((address_space(1))) void*)g,
      (__attribute__((address_space(3))) void*)lds, 16, 0, 0);
}

// prep: cb fp32 -> (a) swizzled bf16 codebook, (b) c2m = -0.5*sum(c^2) (argmax form)
// swz layout: [s*1024+cw][slot'][8 bf16], slot' = slot ^ (cw&7)
__global__ void prep_kernel(const float* __restrict__ cb, u16* __restrict__ swz,
                            float* __restrict__ c2m) {
  int idx = blockIdx.x * BDIM + threadIdx.x;  // s*1024+cw
  int cw = idx & (Kv - 1);
  const float4* src = (const float4*)(cb + (size_t)idx * Dv);
  float v[64];
  float s2 = 0.f;
#pragma unroll
  for (int i = 0; i < 16; ++i) {
    float4 f = src[i];
    v[i * 4 + 0] = f.x; v[i * 4 + 1] = f.y; v[i * 4 + 2] = f.z; v[i * 4 + 3] = f.w;
    s2 += f.x * f.x + f.y * f.y + f.z * f.z + f.w * f.w;
  }
  c2m[idx] = -0.5f * s2;
  uint4* out = (uint4*)(swz + (size_t)idx * Dv);
#pragma unroll
  for (int slot = 0; slot < 8; ++slot) {
    int slotp = slot ^ (cw & 7);
    u32 w[4];
#pragma unroll
    for (int p = 0; p < 4; ++p)
      w[p] = (u32)bf16rne(v[slot * 8 + p * 2]) | ((u32)bf16rne(v[slot * 8 + p * 2 + 1]) << 16);
    uint4 pk; pk.x = w[0]; pk.y = w[1]; pk.z = w[2]; pk.w = w[3];
    out[slotp] = pk;
  }
}

// main: block = 256 rows x 1 subspace; wave = 64 rows x all 1024 codewords.
// score = <x,c> - 0.5*c2 via mfma(A=cb_bf16, B=x_bf16, C=c2m); lane-local argMAX.
// launch_bounds(256,4): cap 128 VGPR — (256,8) forced a 32-VGPR fit and spilled
// xf to scratch (780MB fetch). Body compiles to ~64 VGPR under this bound, so
// real occupancy is still 7-8 blocks/CU via the 20KB LDS footprint.
__global__ __launch_bounds__(BDIM, 4) void pq_mfma(
    const float* __restrict__ x, const float* __restrict__ cb,
    const u16* __restrict__ swz, const float* __restrict__ c2m_g,
    float* __restrict__ quant, float* __restrict__ devpart) {
  __shared__ __attribute__((aligned(16))) u16 cb_lds[2][64 * Dv];  // 2 x 8KB
  __shared__ __attribute__((aligned(16))) float c2_lds[Kv];        // 4KB

  const int tid = threadIdx.x;
  const int s = blockIdx.y;
  const int row0 = blockIdx.x * 256;
  const int wave = tid >> 6, lane = tid & 63;
  const int l15 = lane & 15, lg = lane >> 4;
  const int slotp0 = lg ^ (lane & 7);
  const int slotp1 = (4 + lg) ^ (lane & 7);

  // stage c2 (4KB, one instr) + chunk 0 (8KB, two instr); linear LDS dest
  gload_lds16(c2m_g + s * Kv + tid * 4, &c2_lds[(tid & ~63) * 4]);
  const u16* swz_s = swz + (size_t)s * Kv * Dv;
#pragma unroll
  for (int it = 0; it < 2; ++it)
    gload_lds16(swz_s + (size_t)(it * BDIM + tid) * 8,
                &cb_lds[0][(it * BDIM + (tid & ~63)) * 8]);

  // x rows -> bf16 fragments + fp32 x2 partials
  bf16x8 xf[4][2];
  float x2p[4];
#pragma unroll
  for (int rg = 0; rg < 4; ++rg) {
    x2p[rg] = 0.f;
    const int row = row0 + wave * 64 + rg * 16 + l15;
    const float* xp = x + (size_t)row * Fv + s * Dv + lg * 8;
#pragma unroll
    for (int h = 0; h < 2; ++h) {
      float4 f0 = *(const float4*)(xp + h * 32);
      float4 f1 = *(const float4*)(xp + h * 32 + 4);
      x2p[rg] += f0.x * f0.x + f0.y * f0.y + f0.z * f0.z + f0.w * f0.w
               + f1.x * f1.x + f1.y * f1.y + f1.z * f1.z + f1.w * f1.w;
      bf16x8 v;
      v[0] = (short)bf16rne(f0.x); v[1] = (short)bf16rne(f0.y);
      v[2] = (short)bf16rne(f0.z); v[3] = (short)bf16rne(f0.w);
      v[4] = (short)bf16rne(f1.x); v[5] = (short)bf16rne(f1.y);
      v[6] = (short)bf16rne(f1.z); v[7] = (short)bf16rne(f1.w);
      xf[rg][h] = v;
    }
  }

  float bestv[4];
  int besti[4];
#pragma unroll
  for (int rg = 0; rg < 4; ++rg) { bestv[rg] = -3.0e38f; besti[rg] = 0; }

  __syncthreads();

  // 16 chunks of 64 codewords, double-buffered
#pragma unroll 2
  for (int c = 0; c < 16; ++c) {
    if (c < 15) {
      const u16* srcb = swz_s + (size_t)(c + 1) * 64 * Dv;
#pragma unroll
      for (int it = 0; it < 2; ++it)
        gload_lds16(srcb + (size_t)(it * BDIM + tid) * 8,
                    &cb_lds[(c + 1) & 1][(it * BDIM + (tid & ~63)) * 8]);
    }
    const u16* cbb = cb_lds[c & 1];
    const int kc = c * 64 + lg * 4;
#pragma unroll
    for (int ct = 0; ct < 4; ++ct) {
      f32x4 c2v = *(const f32x4*)&c2_lds[c * 64 + ct * 16 + lg * 4];
      const u16* ap = &cbb[(ct * 16 + l15) * Dv];
      bf16x8 a0 = *(const bf16x8*)&ap[slotp0 * 8];
      bf16x8 a1 = *(const bf16x8*)&ap[slotp1 * 8];
#pragma unroll
      for (int rg = 0; rg < 4; ++rg) {
        f32x4 acc = __builtin_amdgcn_mfma_f32_16x16x32_bf16(a0, xf[rg][0], c2v, 0, 0, 0);
        acc = __builtin_amdgcn_mfma_f32_16x16x32_bf16(a1, xf[rg][1], acc, 0, 0, 0);
#pragma unroll
        for (int r = 0; r < 4; ++r) {
          float v = acc[r];
          int ki = kc + ct * 16 + r;
          bool p = v > bestv[rg];
          bestv[rg] = p ? v : bestv[rg];
          besti[rg] = p ? ki : besti[rg];
        }
      }
    }
    __syncthreads();
  }

  // cross-lane argmax + x2 reduce over lg (cols l15 preserved)
#pragma unroll
  for (int rg = 0; rg < 4; ++rg) {
    float bv = bestv[rg]; int bi = besti[rg]; float xx = x2p[rg];
#pragma unroll
    for (int st = 0; st < 2; ++st) {
      const int m = st == 0 ? 16 : 32;
      float ov = __shfl_xor(bv, m, 64);
      int oi = __shfl_xor(bi, m, 64);
      xx += __shfl_xor(xx, m, 64);
      bool p = (ov > bv) || (ov == bv && oi < bi);
      bv = p ? ov : bv; bi = p ? oi : bi;
    }
    bestv[rg] = bv; besti[rg] = bi; x2p[rg] = xx;
  }

  // dev partial: dist_row = x2 - 2*bestmax
  float dev = 0.f;
#pragma unroll
  for (int rg = 0; rg < 4; ++rg) dev += x2p[rg] - 2.f * bestv[rg];
#pragma unroll
  for (int m = 1; m <= 8; m <<= 1) dev += __shfl_xor(dev, m, 64);
  if (lane == 0)
    devpart[((size_t)blockIdx.y * gridDim.x + blockIdx.x) * 4 + wave] = dev;

  // redistribute best indices via LDS (reuse buf0; last compute buffer was buf1,
  // and the final loop barrier means every wave is done with buf0)
  int* idx_sh = (int*)&cb_lds[0][0];
  if (lg == 0) {
#pragma unroll
    for (int rg = 0; rg < 4; ++rg) idx_sh[wave * 64 + rg * 16 + l15] = besti[rg];
  }

  // coalesced quant write: instr i covers rows i*4+(lane>>4); each 16-lane group
  // reads/writes a full 256B contiguous segment (full 64B sectors, no RFO)
  const float* cbs = cb + (size_t)s * Kv * Dv;
  float* qbase = quant + (size_t)(row0 + wave * 64) * Fv + s * Dv;
#pragma unroll
  for (int i = 0; i < 16; ++i) {
    int rl = i * 4 + (lane >> 4);
    int k = idx_sh[wave * 64 + rl];
    float4 v = *(const float4*)(cbs + (size_t)k * Dv + (lane & 15) * 4);
    *(float4*)(qbase + (size_t)rl * Fv + (lane & 15) * 4) = v;
  }
}

__global__ void dev_reduce(const float* __restrict__ part, float* __restrict__ out) {
  __shared__ float sred[256];
  int tid = threadIdx.x;
  float s = 0.f;
  for (int i = tid; i < 8192; i += 256) s += part[i];
  sred[tid] = s;
  __syncthreads();
  for (int off = 128; off > 0; off >>= 1) {
    if (tid < off) sred[tid] += sred[tid + off];
    __syncthreads();
  }
  if (tid == 0) out[0] = sred[0] * (1.25f / 4194304.0f);
}

extern "C" void kernel_launch(void* const* d_in, const int* in_sizes, int n_in,
                              void* d_out, int out_size, void* d_ws, size_t ws_size,
                              hipStream_t stream) {
  const float* x = (const float*)d_in[0];   // (B,N,F) fp32
  const float* cb = (const float*)d_in[1];  // (S,K,D) fp32
  float* quant = (float*)d_out;
  float* dev = quant + (size_t)Mv * Fv;

  // ws: swz bf16 codebook (1MB), c2m (32KB), dev partials (32KB)
  u16* swz = (u16*)d_ws;
  float* c2m = (float*)(swz + (size_t)Sv * Kv * Dv);
  float* part = c2m + Sv * Kv;

  prep_kernel<<<(Sv * Kv) / BDIM, BDIM, 0, stream>>>(cb, swz, c2m);
  dim3 grid(Mv / 256, Sv);
  pq_mfma<<<grid, BDIM, 0, stream>>>(x, cb, swz, c2m, quant, part);
  dev_reduce<<<1, 256, 0, stream>>>(part, dev);
}